// Round 1
// baseline (1899.092 us; speedup 1.0000x reference)
//
#include <hip/hip_runtime.h>
#include <stdint.h>

#define B_  8
#define S_  8192
#define D_  512
#define NB_ 16
#define M_  (B_*S_)   // 65536 rows

typedef short bf16x8 __attribute__((ext_vector_type(8)));
typedef float f32x4  __attribute__((ext_vector_type(4)));

static __device__ __forceinline__ unsigned short f2bf(float f) {
  unsigned int u = __float_as_uint(f);
  u += 0x7fff + ((u >> 16) & 1);   // RNE
  return (unsigned short)(u >> 16);
}

__global__ __launch_bounds__(256) void zero_kernel(float* p, int n) {
  int i = blockIdx.x * 256 + threadIdx.x;
  if (i < n) p[i] = 0.f;
}

// Column mean accumulate: acc[b*D+d] += sum_{s in block chunk} x[b][s][d]
__global__ __launch_bounds__(512) void colmean_kernel(const float* __restrict__ x,
                                                      float* __restrict__ acc) {
  int b = blockIdx.x, d = threadIdx.x;
  const float* p = x + ((size_t)b * S_ + (size_t)blockIdx.y * 512) * D_ + d;
  float s = 0.f;
  #pragma unroll 8
  for (int i = 0; i < 512; i++) s += p[(size_t)i * D_];
  atomicAdd(&acc[b * D_ + d], s);
}

// wave0: embodied selector, wave1: disembodied. out[0..1]=emb top2, out[2..3]=dis top2
__global__ __launch_bounds__(128) void top2_kernel(const float* __restrict__ embAcc,
                                                   const float* __restrict__ embW,
                                                   const float* __restrict__ embB,
                                                   const float* __restrict__ disAcc,
                                                   const float* __restrict__ disW,
                                                   const float* __restrict__ disB,
                                                   int* __restrict__ out) {
  int wave = threadIdx.x >> 6, lane = threadIdx.x & 63;
  const float* acc = wave ? disAcc : embAcc;
  const float* W   = wave ? disW   : embW;
  const float* bb  = wave ? disB   : embB;
  const float invS = 1.f / (float)S_;
  float logit[NB_];
  for (int nb = 0; nb < NB_; nb++) {
    float s = 0.f;
    for (int d = lane; d < D_; d += 64) s += acc[d] * invS * W[d * NB_ + nb];
    for (int o = 32; o; o >>= 1) s += __shfl_xor(s, o);
    logit[nb] = s + bb[nb];
  }
  if (lane == 0) {
    int i0 = 0;
    for (int i = 1; i < NB_; i++) if (logit[i] > logit[i0]) i0 = i;
    int i1 = (i0 == 0) ? 1 : 0;
    for (int i = 0; i < NB_; i++) if (i != i0 && logit[i] > logit[i1]) i1 = i;
    out[wave * 2 + 0] = i0;
    out[wave * 2 + 1] = i1;
  }
}

// LayerNorm (dynamic block idx for gamma/beta) + cast to bf16. One wave per row.
__global__ __launch_bounds__(256) void ln_cast_kernel(const float* __restrict__ x,
                                                      const float* __restrict__ gB,
                                                      const float* __restrict__ bB,
                                                      const int* __restrict__ idxPtr,
                                                      unsigned short* __restrict__ out) {
  int row  = blockIdx.x * 4 + (threadIdx.x >> 6);
  int lane = threadIdx.x & 63;
  const float4* xr = (const float4*)(x + (size_t)row * D_ + lane * 8);
  float4 v0 = xr[0], v1 = xr[1];
  float s  = v0.x + v0.y + v0.z + v0.w + v1.x + v1.y + v1.z + v1.w;
  float sq = v0.x*v0.x + v0.y*v0.y + v0.z*v0.z + v0.w*v0.w
           + v1.x*v1.x + v1.y*v1.y + v1.z*v1.z + v1.w*v1.w;
  for (int o = 32; o; o >>= 1) { s += __shfl_xor(s, o); sq += __shfl_xor(sq, o); }
  float mean = s * (1.f / D_);
  float var  = sq * (1.f / D_) - mean * mean;
  float rstd = rsqrtf(var + 1e-5f);
  int idx = *idxPtr;
  const float4* g4 = (const float4*)(gB + (size_t)idx * D_ + lane * 8);
  const float4* b4 = (const float4*)(bB + (size_t)idx * D_ + lane * 8);
  float4 g0 = g4[0], g1 = g4[1], c0 = b4[0], c1 = b4[1];
  float xv[8] = {v0.x, v0.y, v0.z, v0.w, v1.x, v1.y, v1.z, v1.w};
  float gv[8] = {g0.x, g0.y, g0.z, g0.w, g1.x, g1.y, g1.z, g1.w};
  float bv[8] = {c0.x, c0.y, c0.z, c0.w, c1.x, c1.y, c1.z, c1.w};
  unsigned short o8[8] __attribute__((aligned(16)));
  #pragma unroll
  for (int k = 0; k < 8; k++) o8[k] = f2bf((xv[k] - mean) * rstd * gv[k] + bv[k]);
  *(uint4*)(out + (size_t)row * D_ + lane * 8) = *(const uint4*)o8;
}

// Gather selected block's weight [K,N] f32 -> transposed bf16 dst[N][K] (LDS tiled)
__global__ __launch_bounds__(256) void wconvert_kernel(const float* __restrict__ srcAll,
                                                       const int* __restrict__ idxPtr,
                                                       int K, int N,
                                                       unsigned short* __restrict__ dst) {
  __shared__ float t[32][33];
  int idx = *idxPtr;
  const float* src = srcAll + (size_t)idx * K * N;
  int k0 = blockIdx.y * 32, n0 = blockIdx.x * 32;
  int tid = threadIdx.x;
  int kl = tid >> 5, nl = tid & 31;  // kl in 0..7
  #pragma unroll
  for (int r = 0; r < 4; r++)
    t[kl + r * 8][nl] = src[(size_t)(k0 + kl + r * 8) * N + n0 + nl];
  __syncthreads();
  #pragma unroll
  for (int r = 0; r < 4; r++)
    dst[(size_t)(n0 + kl + r * 8) * K + k0 + nl] = f2bf(t[nl][kl + r * 8]);
}

// C[M,N] = A[M,K](bf16) @ Bt[N,K](bf16)^T with fused epilogues.
// EPI 0: bout = bf16(tanh(acc+bias))                         (emb gemm1)
// EPI 1: fout = hin + (acc+bias)*(1+0.1*torsion)*0.3         (emb gemm2)
// EPI 2: fout = hin + 0.5*((acc+bias+0.2*delayed)*(1+0.05*torsion))  (dis attn)
// EPI 3: bout = bf16(gelu_exact(acc+bias))                   (dis ff1)
// EPI 4: fout = hin + 0.5*(acc+bias)                         (dis ff2)
template<int EPI>
__global__ __launch_bounds__(256) void gemm_kernel(const unsigned short* __restrict__ A,
                                                   const unsigned short* __restrict__ Bt,
                                                   int K, int N,
                                                   const int* __restrict__ idxPtr,
                                                   const float* __restrict__ biasBase,
                                                   const float* __restrict__ hin,
                                                   float* __restrict__ fout,
                                                   unsigned short* __restrict__ bout,
                                                   const float* __restrict__ torsion,
                                                   const float* __restrict__ dAcc) {
  __shared__ __align__(16) unsigned short As[128 * 32];
  __shared__ __align__(16) unsigned short Bs[128 * 32];
  const int tid  = threadIdx.x;
  const int wave = tid >> 6, lane = tid & 63;
  const int quad = lane >> 4, l16 = lane & 15;
  const int wm = (wave >> 1) * 64, wn = (wave & 1) * 64;
  const int m0 = blockIdx.x * 128, n0 = blockIdx.y * 128;
  const int r0  = tid >> 2;            // staging row (0..63), also row+64
  const int seg = (tid & 3) * 8;       // 8-element (16B) segment within 32-wide K tile
  const unsigned short* Ag = A  + (size_t)(m0 + r0) * K + seg;
  const unsigned short* Bg = Bt + (size_t)(n0 + r0) * K + seg;

  f32x4 acc[4][4] = {};
  for (int kt = 0; kt < K; kt += 32) {
    uint4 a0 = *(const uint4*)(Ag + kt);
    uint4 a1 = *(const uint4*)(Ag + (size_t)64 * K + kt);
    uint4 b0 = *(const uint4*)(Bg + kt);
    uint4 b1 = *(const uint4*)(Bg + (size_t)64 * K + kt);
    *(uint4*)(&As[(size_t)r0 * 32 + seg])        = a0;
    *(uint4*)(&As[(size_t)(r0 + 64) * 32 + seg]) = a1;
    *(uint4*)(&Bs[(size_t)r0 * 32 + seg])        = b0;
    *(uint4*)(&Bs[(size_t)(r0 + 64) * 32 + seg]) = b1;
    __syncthreads();
    bf16x8 af[4], bfr[4];
    #pragma unroll
    for (int i = 0; i < 4; i++)
      af[i] = *(const bf16x8*)(&As[(size_t)(wm + i * 16 + l16) * 32 + quad * 8]);
    #pragma unroll
    for (int j = 0; j < 4; j++)
      bfr[j] = *(const bf16x8*)(&Bs[(size_t)(wn + j * 16 + l16) * 32 + quad * 8]);
    #pragma unroll
    for (int i = 0; i < 4; i++)
      #pragma unroll
      for (int j = 0; j < 4; j++)
        acc[i][j] = __builtin_amdgcn_mfma_f32_16x16x32_bf16(af[i], bfr[j], acc[i][j], 0, 0, 0);
    __syncthreads();
  }

  const int idx = *idxPtr;
  const float* bias = biasBase + (size_t)idx * N;
  const float invS = 1.f / (float)S_;
  #pragma unroll
  for (int i = 0; i < 4; i++) {
    int rowb = m0 + wm + i * 16 + quad * 4;
    #pragma unroll
    for (int j = 0; j < 4; j++) {
      int col = n0 + wn + j * 16 + l16;
      float bc = bias[col];
      #pragma unroll
      for (int r = 0; r < 4; r++) {
        int row = rowb + r;
        size_t off = (size_t)row * N + col;
        float v = acc[i][j][r] + bc;
        if constexpr (EPI == 0) {
          bout[off] = f2bf(tanhf(v));
        } else if constexpr (EPI == 1) {
          int b = row >> 13;  // S = 8192
          float t = 1.f + 0.1f * torsion[b * D_ + col];
          fout[off] = hin[off] + v * t * 0.3f;
        } else if constexpr (EPI == 2) {
          int b = row >> 13;
          float t = 1.f + 0.05f * torsion[b * D_ + col];
          float h1 = (v + 0.2f * dAcc[b * D_ + col] * invS) * t;
          fout[off] = hin[off] + 0.5f * h1;
        } else if constexpr (EPI == 3) {
          float gl = 0.5f * v * (1.f + erff(v * 0.70710678118654752f));
          bout[off] = f2bf(gl);
        } else {
          fout[off] = hin[off] + 0.5f * v;
        }
      }
    }
  }
}

extern "C" void kernel_launch(void* const* d_in, const int* in_sizes, int n_in,
                              void* d_out, int out_size, void* d_ws, size_t ws_size,
                              hipStream_t stream) {
  const float* emb_input  = (const float*)d_in[0];
  const float* dis_input  = (const float*)d_in[1];
  const float* torsion    = (const float*)d_in[2];
  // d_in[3] dis_unlocked (=1, static), d_in[4] delay_steps: unused
  const float* emb_sel_W  = (const float*)d_in[5];
  const float* emb_sel_b  = (const float*)d_in[6];
  const float* emb_ln_g   = (const float*)d_in[7];
  const float* emb_ln_b   = (const float*)d_in[8];
  const float* emb_w1     = (const float*)d_in[9];
  const float* emb_b1     = (const float*)d_in[10];
  const float* emb_w2     = (const float*)d_in[11];
  const float* emb_b2     = (const float*)d_in[12];
  const float* dis_sel_W  = (const float*)d_in[13];
  const float* dis_sel_b  = (const float*)d_in[14];
  const float* dis_ln1_g  = (const float*)d_in[15];
  const float* dis_ln1_b  = (const float*)d_in[16];
  const float* dis_attn_W = (const float*)d_in[17];
  const float* dis_attn_b = (const float*)d_in[18];
  const float* dis_ln2_g  = (const float*)d_in[19];
  const float* dis_ln2_b  = (const float*)d_in[20];
  const float* dis_ff1_W  = (const float*)d_in[21];
  const float* dis_ff1_b  = (const float*)d_in[22];
  const float* dis_ff2_W  = (const float*)d_in[23];
  const float* dis_ff2_b  = (const float*)d_in[24];

  // workspace carve (needs ~138 MB)
  char* w = (char*)d_ws;
  float* accE = (float*)w;                 // 16 KB  (B*D sums, only b=0 used)
  float* accD = (float*)(w + 16384);       // 16 KB
  int*   top  = (int*)(w + 32768);         // [embTop0, embTop1, disTop0, disTop1]
  size_t o = 33024;
  unsigned short* w1t   = (unsigned short*)(w + o); o += 524288;   // [512][512] bf16
  unsigned short* w2t   = (unsigned short*)(w + o); o += 524288;
  unsigned short* attnT = (unsigned short*)(w + o); o += 524288;
  unsigned short* ff1T  = (unsigned short*)(w + o); o += 1048576;  // [1024][512]
  unsigned short* ff2T  = (unsigned short*)(w + o); o += 1048576;  // [512][1024]
  unsigned short* Abuf  = (unsigned short*)(w + o); o += (size_t)M_ * D_ * 2;  // 67 MB
  unsigned short* T1    = (unsigned short*)(w + o); o += (size_t)M_ * D_ * 2;  // 67 MB

  float* outEmb = (float*)d_out;
  float* outDis = outEmb + (size_t)M_ * D_;
  // dis branch runs FIRST: emb half of d_out doubles as the [M,1024] bf16 gelu buffer
  unsigned short* Gbuf = (unsigned short*)d_out;

  zero_kernel<<<32, 256, 0, stream>>>(accE, 2 * B_ * D_);
  colmean_kernel<<<dim3(1, 16), 512, 0, stream>>>(emb_input, accE);  // only b=0 needed
  colmean_kernel<<<dim3(8, 16), 512, 0, stream>>>(dis_input, accD);
  top2_kernel<<<1, 128, 0, stream>>>(accE, emb_sel_W, emb_sel_b,
                                     accD, dis_sel_W, dis_sel_b, top);

  // ---- disembodied branch (2 selected blocks, sequential)
  for (int s = 0; s < 2; s++) {
    const int* di = top + 2 + s;
    const float* dh = (s == 0) ? dis_input : outDis;
    wconvert_kernel<<<dim3(16, 16), 256, 0, stream>>>(dis_attn_W, di, 512, 512, attnT);
    wconvert_kernel<<<dim3(32, 16), 256, 0, stream>>>(dis_ff1_W,  di, 512, 1024, ff1T);
    wconvert_kernel<<<dim3(16, 32), 256, 0, stream>>>(dis_ff2_W,  di, 1024, 512, ff2T);
    ln_cast_kernel<<<M_ / 4, 256, 0, stream>>>(dh, dis_ln1_g, dis_ln1_b, di, Abuf);
    gemm_kernel<2><<<dim3(512, 4), 256, 0, stream>>>(Abuf, attnT, 512, 512, di,
        dis_attn_b, dh, outDis, nullptr, torsion, accD);
    ln_cast_kernel<<<M_ / 4, 256, 0, stream>>>(outDis, dis_ln2_g, dis_ln2_b, di, Abuf);
    gemm_kernel<3><<<dim3(512, 8), 256, 0, stream>>>(Abuf, ff1T, 512, 1024, di,
        dis_ff1_b, nullptr, nullptr, Gbuf, nullptr, nullptr);
    gemm_kernel<4><<<dim3(512, 4), 256, 0, stream>>>(Gbuf, ff2T, 1024, 512, di,
        dis_ff2_b, outDis, outDis, nullptr, nullptr, nullptr);
  }

  // ---- embodied branch (overwrites emb half of d_out, which is now free)
  for (int s = 0; s < 2; s++) {
    const int* ei = top + s;
    const float* h = (s == 0) ? emb_input : outEmb;
    wconvert_kernel<<<dim3(16, 16), 256, 0, stream>>>(emb_w1, ei, 512, 512, w1t);
    wconvert_kernel<<<dim3(16, 16), 256, 0, stream>>>(emb_w2, ei, 512, 512, w2t);
    ln_cast_kernel<<<M_ / 4, 256, 0, stream>>>(h, emb_ln_g, emb_ln_b, ei, Abuf);
    gemm_kernel<0><<<dim3(512, 4), 256, 0, stream>>>(Abuf, w1t, 512, 512, ei,
        emb_b1, nullptr, nullptr, T1, nullptr, nullptr);
    gemm_kernel<1><<<dim3(512, 4), 256, 0, stream>>>(T1, w2t, 512, 512, ei,
        emb_b2, h, outEmb, nullptr, torsion, nullptr);
  }
}

// Round 2
// 1811.174 us; speedup vs baseline: 1.0485x; 1.0485x over previous
//
#include <hip/hip_runtime.h>
#include <stdint.h>

#define B_  8
#define S_  8192
#define D_  512
#define NB_ 16
#define M_  (B_*S_)   // 65536 rows

typedef short bf16x8 __attribute__((ext_vector_type(8)));
typedef float f32x4  __attribute__((ext_vector_type(4)));

static __device__ __forceinline__ unsigned short f2bf(float f) {
  unsigned int u = __float_as_uint(f);
  u += 0x7fff + ((u >> 16) & 1);   // RNE
  return (unsigned short)(u >> 16);
}

// async global->LDS, 16B per lane. LDS dest is wave-uniform base + lane*16.
static __device__ __forceinline__ void async_copy16(const unsigned short* g,
                                                    unsigned short* l) {
  auto* g1 = reinterpret_cast<const __attribute__((address_space(1))) uint32_t*>(
      reinterpret_cast<uintptr_t>(g));
  auto* l3 = reinterpret_cast<__attribute__((address_space(3))) uint32_t*>(
      reinterpret_cast<uintptr_t>(l));
  __builtin_amdgcn_global_load_lds(g1, l3, 16, 0, 0);
}

__global__ __launch_bounds__(256) void zero_kernel(float* p, int n) {
  int i = blockIdx.x * 256 + threadIdx.x;
  if (i < n) p[i] = 0.f;
}

// Column mean accumulate: acc[b*D+d] += sum_{s in block chunk} x[b][s][d]
__global__ __launch_bounds__(512) void colmean_kernel(const float* __restrict__ x,
                                                      float* __restrict__ acc) {
  int b = blockIdx.x, d = threadIdx.x;
  const float* p = x + ((size_t)b * S_ + (size_t)blockIdx.y * 512) * D_ + d;
  float s = 0.f;
  #pragma unroll 8
  for (int i = 0; i < 512; i++) s += p[(size_t)i * D_];
  atomicAdd(&acc[b * D_ + d], s);
}

// wave0: embodied selector, wave1: disembodied. out[0..1]=emb top2, out[2..3]=dis top2
__global__ __launch_bounds__(128) void top2_kernel(const float* __restrict__ embAcc,
                                                   const float* __restrict__ embW,
                                                   const float* __restrict__ embB,
                                                   const float* __restrict__ disAcc,
                                                   const float* __restrict__ disW,
                                                   const float* __restrict__ disB,
                                                   int* __restrict__ out) {
  int wave = threadIdx.x >> 6, lane = threadIdx.x & 63;
  const float* acc = wave ? disAcc : embAcc;
  const float* W   = wave ? disW   : embW;
  const float* bb  = wave ? disB   : embB;
  const float invS = 1.f / (float)S_;
  float logit[NB_];
  for (int nb = 0; nb < NB_; nb++) {
    float s = 0.f;
    for (int d = lane; d < D_; d += 64) s += acc[d] * invS * W[d * NB_ + nb];
    for (int o = 32; o; o >>= 1) s += __shfl_xor(s, o);
    logit[nb] = s + bb[nb];
  }
  if (lane == 0) {
    int i0 = 0;
    for (int i = 1; i < NB_; i++) if (logit[i] > logit[i0]) i0 = i;
    int i1 = (i0 == 0) ? 1 : 0;
    for (int i = 0; i < NB_; i++) if (i != i0 && logit[i] > logit[i1]) i1 = i;
    out[wave * 2 + 0] = i0;
    out[wave * 2 + 1] = i1;
  }
}

// LayerNorm (dynamic block idx for gamma/beta) + cast to bf16. One wave per row.
__global__ __launch_bounds__(256) void ln_cast_kernel(const float* __restrict__ x,
                                                      const float* __restrict__ gB,
                                                      const float* __restrict__ bB,
                                                      const int* __restrict__ idxPtr,
                                                      unsigned short* __restrict__ out) {
  int row  = blockIdx.x * 4 + (threadIdx.x >> 6);
  int lane = threadIdx.x & 63;
  const float4* xr = (const float4*)(x + (size_t)row * D_ + lane * 8);
  float4 v0 = xr[0], v1 = xr[1];
  float s  = v0.x + v0.y + v0.z + v0.w + v1.x + v1.y + v1.z + v1.w;
  float sq = v0.x*v0.x + v0.y*v0.y + v0.z*v0.z + v0.w*v0.w
           + v1.x*v1.x + v1.y*v1.y + v1.z*v1.z + v1.w*v1.w;
  for (int o = 32; o; o >>= 1) { s += __shfl_xor(s, o); sq += __shfl_xor(sq, o); }
  float mean = s * (1.f / D_);
  float var  = sq * (1.f / D_) - mean * mean;
  float rstd = rsqrtf(var + 1e-5f);
  int idx = *idxPtr;
  const float4* g4 = (const float4*)(gB + (size_t)idx * D_ + lane * 8);
  const float4* b4 = (const float4*)(bB + (size_t)idx * D_ + lane * 8);
  float4 g0 = g4[0], g1 = g4[1], c0 = b4[0], c1 = b4[1];
  float xv[8] = {v0.x, v0.y, v0.z, v0.w, v1.x, v1.y, v1.z, v1.w};
  float gv[8] = {g0.x, g0.y, g0.z, g0.w, g1.x, g1.y, g1.z, g1.w};
  float bv[8] = {c0.x, c0.y, c0.z, c0.w, c1.x, c1.y, c1.z, c1.w};
  unsigned short o8[8] __attribute__((aligned(16)));
  #pragma unroll
  for (int k = 0; k < 8; k++) o8[k] = f2bf((xv[k] - mean) * rstd * gv[k] + bv[k]);
  *(uint4*)(out + (size_t)row * D_ + lane * 8) = *(const uint4*)o8;
}

// Gather selected block's weight [K,N] f32 -> transposed bf16 dst[N][K] (LDS tiled)
__global__ __launch_bounds__(256) void wconvert_kernel(const float* __restrict__ srcAll,
                                                       const int* __restrict__ idxPtr,
                                                       int K, int N,
                                                       unsigned short* __restrict__ dst) {
  __shared__ float t[32][33];
  int idx = *idxPtr;
  const float* src = srcAll + (size_t)idx * K * N;
  int k0 = blockIdx.y * 32, n0 = blockIdx.x * 32;
  int tid = threadIdx.x;
  int kl = tid >> 5, nl = tid & 31;  // kl in 0..7
  #pragma unroll
  for (int r = 0; r < 4; r++)
    t[kl + r * 8][nl] = src[(size_t)(k0 + kl + r * 8) * N + n0 + nl];
  __syncthreads();
  #pragma unroll
  for (int r = 0; r < 4; r++)
    dst[(size_t)(n0 + kl + r * 8) * K + k0 + nl] = f2bf(t[nl][kl + r * 8]);
}

// C[M,N] = A[M,K](bf16) @ Bt[N,K](bf16)^T with fused epilogues.
// Staging via global_load_lds width=16; XOR bank-swizzle on 8-elem K-segments;
// XCD-aware 1D tile swizzle (each XCD owns a contiguous M range for L2 A-reuse).
// EPI 0: bout = bf16(tanh(acc+bias))                         (emb gemm1)
// EPI 1: fout = hin + (acc+bias)*(1+0.1*torsion)*0.3         (emb gemm2)
// EPI 2: fout = hin + 0.5*((acc+bias+0.2*delayed)*(1+0.05*torsion))  (dis attn)
// EPI 3: bout = bf16(gelu_exact(acc+bias))                   (dis ff1)
// EPI 4: fout = hin + 0.5*(acc+bias)                         (dis ff2)
template<int EPI>
__global__ __launch_bounds__(256) void gemm_kernel(const unsigned short* __restrict__ A,
                                                   const unsigned short* __restrict__ Bt,
                                                   int K, int N,
                                                   const int* __restrict__ idxPtr,
                                                   const float* __restrict__ biasBase,
                                                   const float* __restrict__ hin,
                                                   float* __restrict__ fout,
                                                   unsigned short* __restrict__ bout,
                                                   const float* __restrict__ torsion,
                                                   const float* __restrict__ dAcc) {
  __shared__ __align__(16) unsigned short As[128 * 32];
  __shared__ __align__(16) unsigned short Bs[128 * 32];
  const int tid  = threadIdx.x;
  const int wave = tid >> 6, lane = tid & 63;
  const int quad = lane >> 4, l16 = lane & 15;
  const int wm = (wave >> 1) * 64, wn = (wave & 1) * 64;

  // XCD-aware tile swizzle: hw round-robins blocks over 8 XCDs; give XCD x the
  // contiguous tile range [x*perX, (x+1)*perX) so its 4MB L2 holds the A rows.
  const int nT  = N >> 7;                 // n tiles (4 or 8), power of 2
  const int lgn = (nT == 4) ? 2 : 3;
  const int perX = gridDim.x >> 3;
  const int tile = (blockIdx.x & 7) * perX + (blockIdx.x >> 3);
  const int m0 = (tile >> lgn) * 128;
  const int n0 = (tile & (nT - 1)) * 128;

  // staging: wave w loads rows [w*16, w*16+16) and [w*16+64, ...) of each tile.
  // lane i -> row w*16 + i/4, logical K-segment ((i&3) ^ sw(row))*8 where
  // sw(row) = (row>>1)&3; HW writes LDS at waveBase + lane*16 (physical slot i&3).
  const int lrow  = lane >> 2;                       // 0..15
  const int segSw = (((lane & 3) ^ ((lane >> 3) & 3)) * 8);
  const unsigned short* AgLo = A  + (size_t)(m0 + wave * 16 + lrow) * K + segSw;
  const unsigned short* AgHi = AgLo + (size_t)64 * K;
  const unsigned short* BgLo = Bt + (size_t)(n0 + wave * 16 + lrow) * K + segSw;
  const unsigned short* BgHi = BgLo + (size_t)64 * K;
  unsigned short* AsLo = &As[(wave * 16) * 32];
  unsigned short* AsHi = &As[(wave * 16 + 64) * 32];
  unsigned short* BsLo = &Bs[(wave * 16) * 32];
  unsigned short* BsHi = &Bs[(wave * 16 + 64) * 32];

  // fragment read swizzle: row r = wm|wn + i*16 + l16 -> sw(r) = (l16>>1)&3
  const int rsw = (l16 >> 1) & 3;

  f32x4 acc[4][4] = {};
  for (int kt = 0; kt < K; kt += 32) {
    async_copy16(AgLo + kt, AsLo);
    async_copy16(AgHi + kt, AsHi);
    async_copy16(BgLo + kt, BsLo);
    async_copy16(BgHi + kt, BsHi);
    __syncthreads();
    bf16x8 af[4], bfr[4];
    #pragma unroll
    for (int i = 0; i < 4; i++)
      af[i] = *(const bf16x8*)(&As[(size_t)(wm + i * 16 + l16) * 32 + (quad ^ rsw) * 8]);
    #pragma unroll
    for (int j = 0; j < 4; j++)
      bfr[j] = *(const bf16x8*)(&Bs[(size_t)(wn + j * 16 + l16) * 32 + (quad ^ rsw) * 8]);
    #pragma unroll
    for (int i = 0; i < 4; i++)
      #pragma unroll
      for (int j = 0; j < 4; j++)
        acc[i][j] = __builtin_amdgcn_mfma_f32_16x16x32_bf16(af[i], bfr[j], acc[i][j], 0, 0, 0);
    __syncthreads();
  }

  const int idx = *idxPtr;
  const float* bias = biasBase + (size_t)idx * N;
  const float invS = 1.f / (float)S_;
  #pragma unroll
  for (int i = 0; i < 4; i++) {
    int rowb = m0 + wm + i * 16 + quad * 4;
    #pragma unroll
    for (int j = 0; j < 4; j++) {
      int col = n0 + wn + j * 16 + l16;
      float bc = bias[col];
      #pragma unroll
      for (int r = 0; r < 4; r++) {
        int row = rowb + r;
        size_t off = (size_t)row * N + col;
        float v = acc[i][j][r] + bc;
        if constexpr (EPI == 0) {
          bout[off] = f2bf(tanhf(v));
        } else if constexpr (EPI == 1) {
          int b = row >> 13;  // S = 8192
          float t = 1.f + 0.1f * torsion[b * D_ + col];
          fout[off] = hin[off] + v * t * 0.3f;
        } else if constexpr (EPI == 2) {
          int b = row >> 13;
          float t = 1.f + 0.05f * torsion[b * D_ + col];
          float h1 = (v + 0.2f * dAcc[b * D_ + col] * invS) * t;
          fout[off] = hin[off] + 0.5f * h1;
        } else if constexpr (EPI == 3) {
          float gl = 0.5f * v * (1.f + erff(v * 0.70710678118654752f));
          bout[off] = f2bf(gl);
        } else {
          fout[off] = hin[off] + 0.5f * v;
        }
      }
    }
  }
}

extern "C" void kernel_launch(void* const* d_in, const int* in_sizes, int n_in,
                              void* d_out, int out_size, void* d_ws, size_t ws_size,
                              hipStream_t stream) {
  const float* emb_input  = (const float*)d_in[0];
  const float* dis_input  = (const float*)d_in[1];
  const float* torsion    = (const float*)d_in[2];
  const float* emb_sel_W  = (const float*)d_in[5];
  const float* emb_sel_b  = (const float*)d_in[6];
  const float* emb_ln_g   = (const float*)d_in[7];
  const float* emb_ln_b   = (const float*)d_in[8];
  const float* emb_w1     = (const float*)d_in[9];
  const float* emb_b1     = (const float*)d_in[10];
  const float* emb_w2     = (const float*)d_in[11];
  const float* emb_b2     = (const float*)d_in[12];
  const float* dis_sel_W  = (const float*)d_in[13];
  const float* dis_sel_b  = (const float*)d_in[14];
  const float* dis_ln1_g  = (const float*)d_in[15];
  const float* dis_ln1_b  = (const float*)d_in[16];
  const float* dis_attn_W = (const float*)d_in[17];
  const float* dis_attn_b = (const float*)d_in[18];
  const float* dis_ln2_g  = (const float*)d_in[19];
  const float* dis_ln2_b  = (const float*)d_in[20];
  const float* dis_ff1_W  = (const float*)d_in[21];
  const float* dis_ff1_b  = (const float*)d_in[22];
  const float* dis_ff2_W  = (const float*)d_in[23];
  const float* dis_ff2_b  = (const float*)d_in[24];

  // workspace carve (needs ~138 MB)
  char* w = (char*)d_ws;
  float* accE = (float*)w;                 // 16 KB  (B*D sums, only b=0 used)
  float* accD = (float*)(w + 16384);       // 16 KB
  int*   top  = (int*)(w + 32768);         // [embTop0, embTop1, disTop0, disTop1]
  size_t o = 33024;
  unsigned short* w1t   = (unsigned short*)(w + o); o += 524288;   // [512][512] bf16
  unsigned short* w2t   = (unsigned short*)(w + o); o += 524288;
  unsigned short* attnT = (unsigned short*)(w + o); o += 524288;
  unsigned short* ff1T  = (unsigned short*)(w + o); o += 1048576;  // [1024][512]
  unsigned short* ff2T  = (unsigned short*)(w + o); o += 1048576;  // [512][1024]
  unsigned short* Abuf  = (unsigned short*)(w + o); o += (size_t)M_ * D_ * 2;  // 67 MB
  unsigned short* T1    = (unsigned short*)(w + o); o += (size_t)M_ * D_ * 2;  // 67 MB

  float* outEmb = (float*)d_out;
  float* outDis = outEmb + (size_t)M_ * D_;
  // dis branch runs FIRST: emb half of d_out doubles as the [M,1024] bf16 gelu buffer
  unsigned short* Gbuf = (unsigned short*)d_out;

  zero_kernel<<<32, 256, 0, stream>>>(accE, 2 * B_ * D_);
  colmean_kernel<<<dim3(1, 16), 512, 0, stream>>>(emb_input, accE);  // only b=0 needed
  colmean_kernel<<<dim3(8, 16), 512, 0, stream>>>(dis_input, accD);
  top2_kernel<<<1, 128, 0, stream>>>(accE, emb_sel_W, emb_sel_b,
                                     accD, dis_sel_W, dis_sel_b, top);

  // ---- disembodied branch (2 selected blocks, sequential)
  for (int s = 0; s < 2; s++) {
    const int* di = top + 2 + s;
    const float* dh = (s == 0) ? dis_input : outDis;
    wconvert_kernel<<<dim3(16, 16), 256, 0, stream>>>(dis_attn_W, di, 512, 512, attnT);
    wconvert_kernel<<<dim3(32, 16), 256, 0, stream>>>(dis_ff1_W,  di, 512, 1024, ff1T);
    wconvert_kernel<<<dim3(16, 32), 256, 0, stream>>>(dis_ff2_W,  di, 1024, 512, ff2T);
    ln_cast_kernel<<<M_ / 4, 256, 0, stream>>>(dh, dis_ln1_g, dis_ln1_b, di, Abuf);
    gemm_kernel<2><<<2048, 256, 0, stream>>>(Abuf, attnT, 512, 512, di,
        dis_attn_b, dh, outDis, nullptr, torsion, accD);
    ln_cast_kernel<<<M_ / 4, 256, 0, stream>>>(outDis, dis_ln2_g, dis_ln2_b, di, Abuf);
    gemm_kernel<3><<<4096, 256, 0, stream>>>(Abuf, ff1T, 512, 1024, di,
        dis_ff1_b, nullptr, nullptr, Gbuf, nullptr, nullptr);
    gemm_kernel<4><<<2048, 256, 0, stream>>>(Gbuf, ff2T, 1024, 512, di,
        dis_ff2_b, outDis, outDis, nullptr, nullptr, nullptr);
  }

  // ---- embodied branch (overwrites emb half of d_out, which is now free)
  for (int s = 0; s < 2; s++) {
    const int* ei = top + s;
    const float* h = (s == 0) ? emb_input : outEmb;
    wconvert_kernel<<<dim3(16, 16), 256, 0, stream>>>(emb_w1, ei, 512, 512, w1t);
    wconvert_kernel<<<dim3(16, 16), 256, 0, stream>>>(emb_w2, ei, 512, 512, w2t);
    ln_cast_kernel<<<M_ / 4, 256, 0, stream>>>(h, emb_ln_g, emb_ln_b, ei, Abuf);
    gemm_kernel<0><<<2048, 256, 0, stream>>>(Abuf, w1t, 512, 512, ei,
        emb_b1, nullptr, nullptr, T1, nullptr, nullptr);
    gemm_kernel<1><<<2048, 256, 0, stream>>>(T1, w2t, 512, 512, ei,
        emb_b2, h, outEmb, nullptr, torsion, nullptr);
  }
}